// Round 4
// baseline (1263.666 us; speedup 1.0000x reference)
//
#include <hip/hip_runtime.h>

#define NEG_SLOPE 0.2f
#define EPSV 1e-16f
#define NHEADS 8
#define NCH 16
#define SCAN_TILE 1024     // 256 threads x 4 elements
#define BKT_SHIFT 8        // 256 nodes per bucket
#define BKT_NODES 256
#define HIST_EPB 16384     // edges per block in bucket-hist

// S1[h] = sum_c W1[h*16+c]*att_src1[h*16+c]; D1 likewise with att_dst1.
__global__ void gat_setup_kernel(const float* __restrict__ W1,
                                 const float* __restrict__ as1,
                                 const float* __restrict__ ad1,
                                 float* __restrict__ S1, float* __restrict__ D1) {
    int h = threadIdx.x;
    if (h < NHEADS) {
        float s = 0.f, d = 0.f;
        for (int c = 0; c < NCH; ++c) {
            float w = W1[h * NCH + c];
            s += w * as1[h * NCH + c];
            d += w * ad1[h * NCH + c];
        }
        S1[h] = s;
        D1[h] = d;
    }
}

// Bucket histogram: LDS-aggregated per block, then few global atomics.
__global__ __launch_bounds__(256) void gat_bkt_hist_kernel(
        const int* __restrict__ ei, int E, int nbuckets,
        int* __restrict__ bkt_cnt) {
    extern __shared__ int hist[];
    int t = threadIdx.x;
    for (int i = t; i < nbuckets; i += 256) hist[i] = 0;
    __syncthreads();
    int base = blockIdx.x * HIST_EPB;
#pragma unroll 4
    for (int k = 0; k < HIST_EPB / 256; ++k) {
        int idx = base + k * 256 + t;
        if (idx < E) atomicAdd(&hist[ei[E + idx] >> BKT_SHIFT], 1);
    }
    __syncthreads();
    for (int i = t; i < nbuckets; i += 256)
        if (hist[i]) atomicAdd(&bkt_cnt[i], hist[i]);
}

// Single-block exclusive scan of bucket counts (nbuckets <= 512);
// writes bkt_off and resets bkt_cnt to 0 (reused as bin cursor).
__global__ __launch_bounds__(512) void gat_bkt_scan_kernel(
        int* __restrict__ bkt_cnt, int* __restrict__ bkt_off, int nb) {
    __shared__ int sh[512];
    int t = threadIdx.x;
    int v = (t < nb) ? bkt_cnt[t] : 0;
    sh[t] = v;
    __syncthreads();
    for (int off = 1; off < 512; off <<= 1) {
        int tmp = (t >= off) ? sh[t - off] : 0;
        __syncthreads();
        sh[t] += tmp;
        __syncthreads();
    }
    if (t < nb) { bkt_off[t] = sh[t] - v; bkt_cnt[t] = 0; }
}

// Bin pass: scatter packed (src<<8 | dst&255) into bucket-contiguous regions.
// Concurrent same-bucket writes take adjacent slots -> L2 line merging.
__global__ __launch_bounds__(256) void gat_bin_kernel(
        const int* __restrict__ ei, int E,
        const int* __restrict__ bkt_off, int* __restrict__ bkt_cnt,
        unsigned int* __restrict__ binned) {
    int i = blockIdx.x * blockDim.x + threadIdx.x;
    if (i >= E) return;
    unsigned int s = (unsigned int)ei[i];
    int d = ei[E + i];
    int b = d >> BKT_SHIFT;
    int p = atomicAdd(&bkt_cnt[b], 1);
    binned[bkt_off[b] + p] = (s << BKT_SHIFT) | (unsigned int)(d & (BKT_NODES - 1));
}

// Per-bucket node counts from binned (LDS hist), coalesced cc write.
// After gat_bin_kernel, bkt_cnt[b] == bucket edge count again.
__global__ __launch_bounds__(256) void gat_count_kernel(
        int N, const unsigned int* __restrict__ binned,
        const int* __restrict__ bkt_off, const int* __restrict__ bkt_cnt,
        int* __restrict__ cc) {
    __shared__ int cnt[BKT_NODES];
    int b = blockIdx.x, t = threadIdx.x;
    cnt[t] = 0;
    __syncthreads();
    int nE = bkt_cnt[b];
    int base = bkt_off[b];
    for (int j = t; j < nE; j += 256)
        atomicAdd(&cnt[binned[base + j] & (BKT_NODES - 1)], 1);
    __syncthreads();
    int node = (b << BKT_SHIFT) + t;
    if (node < N) cc[node] = cnt[t];
}

// Scan phase A: per-block tile sums over cc.
__global__ __launch_bounds__(256) void gat_scan_a_kernel(
        const int* __restrict__ cc, int N, int* __restrict__ bsum) {
    int b = blockIdx.x, t = threadIdx.x;
    int base = b * SCAN_TILE + t * 4;
    int s = 0;
    if (base + 3 < N) {
        int4 v = *(const int4*)(cc + base);
        s = v.x + v.y + v.z + v.w;
    } else {
        for (int k = 0; k < 4; ++k) if (base + k < N) s += cc[base + k];
    }
    __shared__ int red[256];
    red[t] = s;
    __syncthreads();
    for (int off = 128; off > 0; off >>= 1) {
        if (t < off) red[t] += red[t + off];
        __syncthreads();
    }
    if (t == 0) bsum[b] = red[0];
}

// Scan phase B: single block exclusive-scans up to 256 block sums in place.
__global__ __launch_bounds__(256) void gat_scan_b_kernel(
        int* __restrict__ bsum, int nb) {
    __shared__ int sh[256];
    int t = threadIdx.x;
    int v = (t < nb) ? bsum[t] : 0;
    sh[t] = v;
    __syncthreads();
    for (int off = 1; off < 256; off <<= 1) {
        int tmp = (t >= off) ? sh[t - off] : 0;
        __syncthreads();
        sh[t] += tmp;
        __syncthreads();
    }
    if (t < nb) bsum[t] = sh[t] - v;   // exclusive
}

// Scan phase C: write row_start only (cc stays as per-node counts).
__global__ __launch_bounds__(256) void gat_scan_c_kernel(
        const int* __restrict__ cc, int N, const int* __restrict__ bsum,
        int* __restrict__ row_start) {
    int b = blockIdx.x, t = threadIdx.x;
    int base = b * SCAN_TILE + t * 4;
    int v0 = 0, v1 = 0, v2 = 0, v3 = 0;
    bool full = (base + 3 < N);
    if (full) {
        int4 q = *(const int4*)(cc + base);
        v0 = q.x; v1 = q.y; v2 = q.z; v3 = q.w;
    } else {
        if (base + 0 < N) v0 = cc[base + 0];
        if (base + 1 < N) v1 = cc[base + 1];
        if (base + 2 < N) v2 = cc[base + 2];
    }
    int s = v0 + v1 + v2 + v3;
    __shared__ int sh[256];
    sh[t] = s;
    __syncthreads();
    for (int off = 1; off < 256; off <<= 1) {
        int tmp = (t >= off) ? sh[t - off] : 0;
        __syncthreads();
        sh[t] += tmp;
        __syncthreads();
    }
    int run = bsum[b] + sh[t] - s;
    int o0 = run; run += v0;
    int o1 = run; run += v1;
    int o2 = run; run += v2;
    int o3 = run;
    if (full) {
        *(int4*)(row_start + base) = make_int4(o0, o1, o2, o3);
    } else {
        if (base + 0 < N) row_start[base + 0] = o0;
        if (base + 1 < N) row_start[base + 1] = o1;
        if (base + 2 < N) row_start[base + 2] = o2;
    }
}

// Per-bucket scatter: LDS cursors seeded from row_start; all CSR writes for
// this block land in one contiguous ~16KB window -> L2 merges them.
__global__ __launch_bounds__(256) void gat_scatter_kernel(
        int N, const unsigned int* __restrict__ binned,
        const int* __restrict__ bkt_off, const int* __restrict__ bkt_cnt,
        const int* __restrict__ row_start,
        int* __restrict__ csr_src) {
    __shared__ int cur[BKT_NODES];
    int b = blockIdx.x, t = threadIdx.x;
    int node = (b << BKT_SHIFT) + t;
    cur[t] = (node < N) ? row_start[node] : 0;
    __syncthreads();
    int nE = bkt_cnt[b];
    int base = bkt_off[b];
    for (int j = t; j < nE; j += 256) {
        unsigned int v = binned[base + j];
        int p = atomicAdd(&cur[v & (BKT_NODES - 1)], 1);
        csr_src[p] = (int)(v >> BKT_SHIFT);
    }
}

// Layer 1: per-node gather, 8 heads in registers, fold self-loop,
// then z -> elu(W1*z+b1) -> dot W2 -> h2[n].
__global__ __launch_bounds__(256) void gat_gather1_kernel(
        int N, const float* __restrict__ x,
        const int* __restrict__ row_start, const int* __restrict__ cc,
        const int* __restrict__ csr_src,
        const float* __restrict__ S1g, const float* __restrict__ D1g,
        const float* __restrict__ W1, const float* __restrict__ b1,
        const float* __restrict__ W2,
        float* __restrict__ h2out) {
    int n = blockIdx.x * blockDim.x + threadIdx.x;
    if (n >= N) return;
    float xn = x[n];
    float S1[NHEADS], A[NHEADS], den[NHEADS], num[NHEADS];
#pragma unroll
    for (int h = 0; h < NHEADS; ++h) {
        S1[h] = S1g[h];
        A[h] = xn * D1g[h];
        float e = xn * S1[h] + A[h];          // self-loop
        e = e > 0.f ? e : NEG_SLOPE * e;
        float ex = __expf(e);
        den[h] = ex + EPSV;
        num[h] = ex * xn;
    }
    int lo = row_start[n], hi = lo + cc[n];
    for (int j = lo; j < hi; ++j) {
        float xs = x[csr_src[j]];
#pragma unroll
        for (int h = 0; h < NHEADS; ++h) {
            float e = xs * S1[h] + A[h];
            e = e > 0.f ? e : NEG_SLOPE * e;
            float ex = __expf(e);
            den[h] += ex;
            num[h] += ex * xs;
        }
    }
    float acc = 0.f;
#pragma unroll
    for (int h = 0; h < NHEADS; ++h) {
        float z = num[h] / den[h];
#pragma unroll
        for (int c = 0; c < NCH; ++c) {
            int k = h * NCH + c;
            float v = W1[k] * z + b1[k];
            v = v > 0.f ? v : (__expf(v) - 1.f);   // elu
            acc += v * W2[k];
        }
    }
    h2out[n] = acc;
}

// Layer 2: single head/channel gather over the same CSR.
__global__ __launch_bounds__(256) void gat_gather2_kernel(
        int N, const float* __restrict__ h2,
        const int* __restrict__ row_start, const int* __restrict__ cc,
        const int* __restrict__ csr_src,
        const float* __restrict__ as2p, const float* __restrict__ ad2p,
        const float* __restrict__ b2,
        float* __restrict__ out) {
    int n = blockIdx.x * blockDim.x + threadIdx.x;
    if (n >= N) return;
    float a_s = as2p[0], a_d = ad2p[0];
    float hn = h2[n];
    float ad = hn * a_d;
    float e = hn * a_s + ad;                  // self-loop
    e = e > 0.f ? e : NEG_SLOPE * e;
    float ex = __expf(e);
    float den = ex + EPSV;
    float num = ex * hn;
    int lo = row_start[n], hi = lo + cc[n];
    for (int j = lo; j < hi; ++j) {
        float hs = h2[csr_src[j]];
        float ee = hs * a_s + ad;
        ee = ee > 0.f ? ee : NEG_SLOPE * ee;
        float exx = __expf(ee);
        den += exx;
        num += exx * hs;
    }
    out[n] = num / den + b2[0];
}

extern "C" void kernel_launch(void* const* d_in, const int* in_sizes, int n_in,
                              void* d_out, int out_size, void* d_ws, size_t ws_size,
                              hipStream_t stream) {
    const float* x   = (const float*)d_in[0];
    const int*   ei  = (const int*)d_in[1];
    const float* W1  = (const float*)d_in[2];
    const float* as1 = (const float*)d_in[3];
    const float* ad1 = (const float*)d_in[4];
    const float* b1  = (const float*)d_in[5];
    const float* W2  = (const float*)d_in[6];
    const float* as2 = (const float*)d_in[7];
    const float* ad2 = (const float*)d_in[8];
    const float* b2  = (const float*)d_in[9];
    float* out = (float*)d_out;

    int N = in_sizes[0];       // 100000
    int E = in_sizes[1] / 2;   // 1600000

    int nbuckets = (N + BKT_NODES - 1) >> BKT_SHIFT;        // 391
    int nscan    = (N + SCAN_TILE - 1) / SCAN_TILE;         // 98
    int nhist    = (E + HIST_EPB - 1) / HIST_EPB;           // 98

    // Workspace: S1[8]f | D1[8]f | h2[N]f | row_start[N]i | cc[N]i |
    // csr_src[E]i | bsum[nscan]i | bkt_cnt[nbuckets]i | bkt_off[nbuckets]i |
    // binned[E]u     (~14 MB)
    float* S1        = (float*)d_ws;
    float* D1        = S1 + 8;
    float* h2        = D1 + 8;
    int*   row_start = (int*)(h2 + N);
    int*   cc        = row_start + N;
    int*   csr_src   = cc + N;
    int*   bsum      = csr_src + E;
    int*   bkt_cnt   = bsum + nscan;
    int*   bkt_off   = bkt_cnt + nbuckets;
    unsigned int* binned = (unsigned int*)(bkt_off + nbuckets);

    hipMemsetAsync(bkt_cnt, 0, (size_t)nbuckets * sizeof(int), stream);

    gat_setup_kernel<<<1, NHEADS, 0, stream>>>(W1, as1, ad1, S1, D1);

    int eb = (E + 255) / 256;
    int nb = (N + 255) / 256;
    size_t hist_lds = (size_t)nbuckets * sizeof(int);

    gat_bkt_hist_kernel<<<nhist, 256, hist_lds, stream>>>(ei, E, nbuckets, bkt_cnt);
    gat_bkt_scan_kernel<<<1, 512, 0, stream>>>(bkt_cnt, bkt_off, nbuckets);
    gat_bin_kernel<<<eb, 256, 0, stream>>>(ei, E, bkt_off, bkt_cnt, binned);
    gat_count_kernel<<<nbuckets, 256, 0, stream>>>(N, binned, bkt_off, bkt_cnt, cc);
    gat_scan_a_kernel<<<nscan, 256, 0, stream>>>(cc, N, bsum);
    gat_scan_b_kernel<<<1, 256, 0, stream>>>(bsum, nscan);
    gat_scan_c_kernel<<<nscan, 256, 0, stream>>>(cc, N, bsum, row_start);
    gat_scatter_kernel<<<nbuckets, 256, 0, stream>>>(N, binned, bkt_off, bkt_cnt,
                                                     row_start, csr_src);
    gat_gather1_kernel<<<nb, 256, 0, stream>>>(N, x, row_start, cc, csr_src,
                                               S1, D1, W1, b1, W2, h2);
    gat_gather2_kernel<<<nb, 256, 0, stream>>>(N, h2, row_start, cc, csr_src,
                                               as2, ad2, b2, out);
}

// Round 5
// 197.284 us; speedup vs baseline: 6.4053x; 6.4053x over previous
//
#include <hip/hip_runtime.h>

#define NEG_SLOPE 0.2f
#define EPSV 1e-16f
#define NHEADS 8
#define NCH 16
#define SCAN_TILE 1024     // 256 threads x 4 elements
#define BKT_SHIFT 8        // 256 nodes per bucket
#define BKT_NODES 256
#define HIST_EPB 16384     // edges per block in bucket-hist
#define BIN_EPB 8192       // edges per block in bin pass (32/thread)
#define MAX_BKT 512

// S1[h] = sum_c W1[h*16+c]*att_src1[h*16+c]; D1 likewise with att_dst1.
__global__ void gat_setup_kernel(const float* __restrict__ W1,
                                 const float* __restrict__ as1,
                                 const float* __restrict__ ad1,
                                 float* __restrict__ S1, float* __restrict__ D1) {
    int h = threadIdx.x;
    if (h < NHEADS) {
        float s = 0.f, d = 0.f;
        for (int c = 0; c < NCH; ++c) {
            float w = W1[h * NCH + c];
            s += w * as1[h * NCH + c];
            d += w * ad1[h * NCH + c];
        }
        S1[h] = s;
        D1[h] = d;
    }
}

// Bucket histogram: LDS-aggregated per block, then few global atomics.
__global__ __launch_bounds__(256) void gat_bkt_hist_kernel(
        const int* __restrict__ ei, int E, int nbuckets,
        int* __restrict__ bkt_cnt) {
    extern __shared__ int hist[];
    int t = threadIdx.x;
    for (int i = t; i < nbuckets; i += 256) hist[i] = 0;
    __syncthreads();
    int base = blockIdx.x * HIST_EPB;
#pragma unroll 4
    for (int k = 0; k < HIST_EPB / 256; ++k) {
        int idx = base + k * 256 + t;
        if (idx < E) atomicAdd(&hist[ei[E + idx] >> BKT_SHIFT], 1);
    }
    __syncthreads();
    for (int i = t; i < nbuckets; i += 256)
        if (hist[i]) atomicAdd(&bkt_cnt[i], hist[i]);
}

// Single-block exclusive scan of bucket counts (nbuckets <= 512);
// writes bkt_off and resets bkt_cnt to 0 (reused as bin cursor).
__global__ __launch_bounds__(512) void gat_bkt_scan_kernel(
        int* __restrict__ bkt_cnt, int* __restrict__ bkt_off, int nb) {
    __shared__ int sh[512];
    int t = threadIdx.x;
    int v = (t < nb) ? bkt_cnt[t] : 0;
    sh[t] = v;
    __syncthreads();
    for (int off = 1; off < 512; off <<= 1) {
        int tmp = (t >= off) ? sh[t - off] : 0;
        __syncthreads();
        sh[t] += tmp;
        __syncthreads();
    }
    if (t < nb) { bkt_off[t] = sh[t] - v; bkt_cnt[t] = 0; }
}

// Bin pass, block-aggregated: LDS histogram + local ranks, ONE global atomic
// per (block, nonempty bucket) to reserve a contiguous range, then clustered
// writes of packed (src<<8 | dst&255).
__global__ __launch_bounds__(256) void gat_bin_kernel(
        const int* __restrict__ ei, int E, int nbuckets,
        const int* __restrict__ bkt_off, int* __restrict__ bkt_cnt,
        unsigned int* __restrict__ binned) {
    __shared__ int hist[MAX_BKT];
    __shared__ int gbase[MAX_BKT];
    int t = threadIdx.x;
    for (int i = t; i < nbuckets; i += 256) hist[i] = 0;
    __syncthreads();
    int base = blockIdx.x * BIN_EPB;
    int lr[BIN_EPB / 256];
#pragma unroll
    for (int k = 0; k < BIN_EPB / 256; ++k) {
        int idx = base + k * 256 + t;
        if (idx < E) lr[k] = atomicAdd(&hist[ei[E + idx] >> BKT_SHIFT], 1);
    }
    __syncthreads();
    // one global cursor atomic per nonempty bucket; fold in bkt_off
    for (int i = t; i < nbuckets; i += 256) {
        int c = hist[i];
        gbase[i] = c ? (bkt_off[i] + atomicAdd(&bkt_cnt[i], c)) : 0;
    }
    __syncthreads();
#pragma unroll
    for (int k = 0; k < BIN_EPB / 256; ++k) {
        int idx = base + k * 256 + t;
        if (idx < E) {
            unsigned int s = (unsigned int)ei[idx];
            int d = ei[E + idx];
            int b = d >> BKT_SHIFT;
            binned[gbase[b] + lr[k]] =
                (s << BKT_SHIFT) | (unsigned int)(d & (BKT_NODES - 1));
        }
    }
}

// Per-bucket node counts from binned (LDS hist), coalesced cc write.
// After gat_bin_kernel, bkt_cnt[b] == bucket edge count again.
__global__ __launch_bounds__(256) void gat_count_kernel(
        int N, const unsigned int* __restrict__ binned,
        const int* __restrict__ bkt_off, const int* __restrict__ bkt_cnt,
        int* __restrict__ cc) {
    __shared__ int cnt[BKT_NODES];
    int b = blockIdx.x, t = threadIdx.x;
    cnt[t] = 0;
    __syncthreads();
    int nE = bkt_cnt[b];
    int base = bkt_off[b];
    for (int j = t; j < nE; j += 256)
        atomicAdd(&cnt[binned[base + j] & (BKT_NODES - 1)], 1);
    __syncthreads();
    int node = (b << BKT_SHIFT) + t;
    if (node < N) cc[node] = cnt[t];
}

// Scan phase A: per-block tile sums over cc.
__global__ __launch_bounds__(256) void gat_scan_a_kernel(
        const int* __restrict__ cc, int N, int* __restrict__ bsum) {
    int b = blockIdx.x, t = threadIdx.x;
    int base = b * SCAN_TILE + t * 4;
    int s = 0;
    if (base + 3 < N) {
        int4 v = *(const int4*)(cc + base);
        s = v.x + v.y + v.z + v.w;
    } else {
        for (int k = 0; k < 4; ++k) if (base + k < N) s += cc[base + k];
    }
    __shared__ int red[256];
    red[t] = s;
    __syncthreads();
    for (int off = 128; off > 0; off >>= 1) {
        if (t < off) red[t] += red[t + off];
        __syncthreads();
    }
    if (t == 0) bsum[b] = red[0];
}

// Scan phase B: single block exclusive-scans up to 256 block sums in place.
__global__ __launch_bounds__(256) void gat_scan_b_kernel(
        int* __restrict__ bsum, int nb) {
    __shared__ int sh[256];
    int t = threadIdx.x;
    int v = (t < nb) ? bsum[t] : 0;
    sh[t] = v;
    __syncthreads();
    for (int off = 1; off < 256; off <<= 1) {
        int tmp = (t >= off) ? sh[t - off] : 0;
        __syncthreads();
        sh[t] += tmp;
        __syncthreads();
    }
    if (t < nb) bsum[t] = sh[t] - v;   // exclusive
}

// Scan phase C: write row_start only (cc stays as per-node counts).
__global__ __launch_bounds__(256) void gat_scan_c_kernel(
        const int* __restrict__ cc, int N, const int* __restrict__ bsum,
        int* __restrict__ row_start) {
    int b = blockIdx.x, t = threadIdx.x;
    int base = b * SCAN_TILE + t * 4;
    int v0 = 0, v1 = 0, v2 = 0, v3 = 0;
    bool full = (base + 3 < N);
    if (full) {
        int4 q = *(const int4*)(cc + base);
        v0 = q.x; v1 = q.y; v2 = q.z; v3 = q.w;
    } else {
        if (base + 0 < N) v0 = cc[base + 0];
        if (base + 1 < N) v1 = cc[base + 1];
        if (base + 2 < N) v2 = cc[base + 2];
    }
    int s = v0 + v1 + v2 + v3;
    __shared__ int sh[256];
    sh[t] = s;
    __syncthreads();
    for (int off = 1; off < 256; off <<= 1) {
        int tmp = (t >= off) ? sh[t - off] : 0;
        __syncthreads();
        sh[t] += tmp;
        __syncthreads();
    }
    int run = bsum[b] + sh[t] - s;
    int o0 = run; run += v0;
    int o1 = run; run += v1;
    int o2 = run; run += v2;
    int o3 = run;
    if (full) {
        *(int4*)(row_start + base) = make_int4(o0, o1, o2, o3);
    } else {
        if (base + 0 < N) row_start[base + 0] = o0;
        if (base + 1 < N) row_start[base + 1] = o1;
        if (base + 2 < N) row_start[base + 2] = o2;
    }
}

// Per-bucket scatter: LDS cursors seeded from row_start; all CSR writes for
// this block land in one contiguous ~16KB window -> L2 merges them.
__global__ __launch_bounds__(256) void gat_scatter_kernel(
        int N, const unsigned int* __restrict__ binned,
        const int* __restrict__ bkt_off, const int* __restrict__ bkt_cnt,
        const int* __restrict__ row_start,
        int* __restrict__ csr_src) {
    __shared__ int cur[BKT_NODES];
    int b = blockIdx.x, t = threadIdx.x;
    int node = (b << BKT_SHIFT) + t;
    cur[t] = (node < N) ? row_start[node] : 0;
    __syncthreads();
    int nE = bkt_cnt[b];
    int base = bkt_off[b];
    for (int j = t; j < nE; j += 256) {
        unsigned int v = binned[base + j];
        int p = atomicAdd(&cur[v & (BKT_NODES - 1)], 1);
        csr_src[p] = (int)(v >> BKT_SHIFT);
    }
}

// Layer 1: per-node gather, 8 heads in registers, fold self-loop,
// then z -> elu(W1*z+b1) -> dot W2 -> h2[n].
__global__ __launch_bounds__(256) void gat_gather1_kernel(
        int N, const float* __restrict__ x,
        const int* __restrict__ row_start, const int* __restrict__ cc,
        const int* __restrict__ csr_src,
        const float* __restrict__ S1g, const float* __restrict__ D1g,
        const float* __restrict__ W1, const float* __restrict__ b1,
        const float* __restrict__ W2,
        float* __restrict__ h2out) {
    int n = blockIdx.x * blockDim.x + threadIdx.x;
    if (n >= N) return;
    float xn = x[n];
    float S1[NHEADS], A[NHEADS], den[NHEADS], num[NHEADS];
#pragma unroll
    for (int h = 0; h < NHEADS; ++h) {
        S1[h] = S1g[h];
        A[h] = xn * D1g[h];
        float e = xn * S1[h] + A[h];          // self-loop
        e = e > 0.f ? e : NEG_SLOPE * e;
        float ex = __expf(e);
        den[h] = ex + EPSV;
        num[h] = ex * xn;
    }
    int lo = row_start[n], hi = lo + cc[n];
    for (int j = lo; j < hi; ++j) {
        float xs = x[csr_src[j]];
#pragma unroll
        for (int h = 0; h < NHEADS; ++h) {
            float e = xs * S1[h] + A[h];
            e = e > 0.f ? e : NEG_SLOPE * e;
            float ex = __expf(e);
            den[h] += ex;
            num[h] += ex * xs;
        }
    }
    float acc = 0.f;
#pragma unroll
    for (int h = 0; h < NHEADS; ++h) {
        float z = num[h] / den[h];
#pragma unroll
        for (int c = 0; c < NCH; ++c) {
            int k = h * NCH + c;
            float v = W1[k] * z + b1[k];
            v = v > 0.f ? v : (__expf(v) - 1.f);   // elu
            acc += v * W2[k];
        }
    }
    h2out[n] = acc;
}

// Layer 2: single head/channel gather over the same CSR.
__global__ __launch_bounds__(256) void gat_gather2_kernel(
        int N, const float* __restrict__ h2,
        const int* __restrict__ row_start, const int* __restrict__ cc,
        const int* __restrict__ csr_src,
        const float* __restrict__ as2p, const float* __restrict__ ad2p,
        const float* __restrict__ b2,
        float* __restrict__ out) {
    int n = blockIdx.x * blockDim.x + threadIdx.x;
    if (n >= N) return;
    float a_s = as2p[0], a_d = ad2p[0];
    float hn = h2[n];
    float ad = hn * a_d;
    float e = hn * a_s + ad;                  // self-loop
    e = e > 0.f ? e : NEG_SLOPE * e;
    float ex = __expf(e);
    float den = ex + EPSV;
    float num = ex * hn;
    int lo = row_start[n], hi = lo + cc[n];
    for (int j = lo; j < hi; ++j) {
        float hs = h2[csr_src[j]];
        float ee = hs * a_s + ad;
        ee = ee > 0.f ? ee : NEG_SLOPE * ee;
        float exx = __expf(ee);
        den += exx;
        num += exx * hs;
    }
    out[n] = num / den + b2[0];
}

extern "C" void kernel_launch(void* const* d_in, const int* in_sizes, int n_in,
                              void* d_out, int out_size, void* d_ws, size_t ws_size,
                              hipStream_t stream) {
    const float* x   = (const float*)d_in[0];
    const int*   ei  = (const int*)d_in[1];
    const float* W1  = (const float*)d_in[2];
    const float* as1 = (const float*)d_in[3];
    const float* ad1 = (const float*)d_in[4];
    const float* b1  = (const float*)d_in[5];
    const float* W2  = (const float*)d_in[6];
    const float* as2 = (const float*)d_in[7];
    const float* ad2 = (const float*)d_in[8];
    const float* b2  = (const float*)d_in[9];
    float* out = (float*)d_out;

    int N = in_sizes[0];       // 100000
    int E = in_sizes[1] / 2;   // 1600000

    int nbuckets = (N + BKT_NODES - 1) >> BKT_SHIFT;        // 391
    int nscan    = (N + SCAN_TILE - 1) / SCAN_TILE;         // 98
    int nhist    = (E + HIST_EPB - 1) / HIST_EPB;           // 98
    int nbin     = (E + BIN_EPB - 1) / BIN_EPB;             // 196

    // Workspace: S1[8]f | D1[8]f | h2[N]f | row_start[N]i | cc[N]i |
    // csr_src[E]i | bsum[nscan]i | bkt_cnt[nbuckets]i | bkt_off[nbuckets]i |
    // binned[E]u     (~14 MB)
    float* S1        = (float*)d_ws;
    float* D1        = S1 + 8;
    float* h2        = D1 + 8;
    int*   row_start = (int*)(h2 + N);
    int*   cc        = row_start + N;
    int*   csr_src   = cc + N;
    int*   bsum      = csr_src + E;
    int*   bkt_cnt   = bsum + nscan;
    int*   bkt_off   = bkt_cnt + nbuckets;
    unsigned int* binned = (unsigned int*)(bkt_off + nbuckets);

    hipMemsetAsync(bkt_cnt, 0, (size_t)nbuckets * sizeof(int), stream);

    gat_setup_kernel<<<1, NHEADS, 0, stream>>>(W1, as1, ad1, S1, D1);

    int nb = (N + 255) / 256;
    size_t hist_lds = (size_t)nbuckets * sizeof(int);

    gat_bkt_hist_kernel<<<nhist, 256, hist_lds, stream>>>(ei, E, nbuckets, bkt_cnt);
    gat_bkt_scan_kernel<<<1, 512, 0, stream>>>(bkt_cnt, bkt_off, nbuckets);
    gat_bin_kernel<<<nbin, 256, 0, stream>>>(ei, E, nbuckets, bkt_off, bkt_cnt,
                                             binned);
    gat_count_kernel<<<nbuckets, 256, 0, stream>>>(N, binned, bkt_off, bkt_cnt, cc);
    gat_scan_a_kernel<<<nscan, 256, 0, stream>>>(cc, N, bsum);
    gat_scan_b_kernel<<<1, 256, 0, stream>>>(bsum, nscan);
    gat_scan_c_kernel<<<nscan, 256, 0, stream>>>(cc, N, bsum, row_start);
    gat_scatter_kernel<<<nbuckets, 256, 0, stream>>>(N, binned, bkt_off, bkt_cnt,
                                                     row_start, csr_src);
    gat_gather1_kernel<<<nb, 256, 0, stream>>>(N, x, row_start, cc, csr_src,
                                               S1, D1, W1, b1, W2, h2);
    gat_gather2_kernel<<<nb, 256, 0, stream>>>(N, h2, row_start, cc, csr_src,
                                               as2, ad2, b2, out);
}